// Round 1
// baseline (129.161 us; speedup 1.0000x reference)
//
#include <hip/hip_runtime.h>
#include <hip/hip_bf16.h>

#define VOCAB 50257
#define HID 512
#define LABELS 64

// ---------------------------------------------------------------------------
// K1: build table M[v][l] = sum_h (w1[h,v] + b1[h]) * w2[l,h]
// Tile: 64 vocab cols x 64 labels per block, K chunked by 32 via LDS.
// 256 threads, each computes a 4x4 (col x label) register tile.
// LDS stride 68 (=64+4): breaks power-of-2 bank aliasing, keeps rows
// 272 B (16-aligned) so float4 LDS reads stay b128.
// ---------------------------------------------------------------------------
__global__ __launch_bounds__(256) void build_table(
    const float* __restrict__ w1,   // [HID][VOCAB]
    const float* __restrict__ b1,   // [HID]
    const float* __restrict__ w2,   // [LABELS][HID]
    float* __restrict__ M)          // [VOCAB][LABELS]
{
    __shared__ float lds_a[32 * 68];  // w1 chunk: [hh][col], with b1 folded in
    __shared__ float lds_b[32 * 68];  // w2^T chunk: [hh][label]

    const int t  = threadIdx.x;
    const int v0 = blockIdx.x * 64;
    const int tx = t & 15;   // col group: cols tx*4 .. tx*4+3
    const int ty = t >> 4;   // label group: labels ty*4 .. ty*4+3

    float acc[4][4];
#pragma unroll
    for (int i = 0; i < 4; ++i)
#pragma unroll
        for (int j = 0; j < 4; ++j) acc[i][j] = 0.f;

    for (int h0 = 0; h0 < HID; h0 += 32) {
        // ---- stage w1 chunk (+b1) and w2^T chunk ----
#pragma unroll
        for (int i = 0; i < 8; ++i) {
            int e   = t + 256 * i;        // 0..2047
            int row = e >> 6;             // hh
            int col = e & 63;             // vocab col within tile
            int v   = v0 + col;
            float a = (v < VOCAB) ? w1[(size_t)(h0 + row) * VOCAB + v] : 0.f;
            lds_a[row * 68 + col] = a + b1[h0 + row];

            int l  = e >> 5;              // label 0..63
            int hh = e & 31;
            lds_b[hh * 68 + l] = w2[l * HID + h0 + hh];
        }
        __syncthreads();

        // ---- compute ----
#pragma unroll
        for (int hh = 0; hh < 32; ++hh) {
            float4 a = *(const float4*)&lds_a[hh * 68 + tx * 4];
            float4 b = *(const float4*)&lds_b[hh * 68 + ty * 4];
            acc[0][0] += a.x * b.x; acc[0][1] += a.x * b.y; acc[0][2] += a.x * b.z; acc[0][3] += a.x * b.w;
            acc[1][0] += a.y * b.x; acc[1][1] += a.y * b.y; acc[1][2] += a.y * b.z; acc[1][3] += a.y * b.w;
            acc[2][0] += a.z * b.x; acc[2][1] += a.z * b.y; acc[2][2] += a.z * b.z; acc[2][3] += a.z * b.w;
            acc[3][0] += a.w * b.x; acc[3][1] += a.w * b.y; acc[3][2] += a.w * b.z; acc[3][3] += a.w * b.w;
        }
        __syncthreads();
    }

    // ---- store: M[(v0+c)][l], c = tx*4+i, l = ty*4+j ----
#pragma unroll
    for (int i = 0; i < 4; ++i) {
        int v = v0 + tx * 4 + i;
        if (v < VOCAB) {
            float4 r = make_float4(acc[i][0], acc[i][1], acc[i][2], acc[i][3]);
            *(float4*)&M[(size_t)v * LABELS + ty * 4] = r;
        }
    }
}

// ---------------------------------------------------------------------------
// K2: out[tok][l] = M[idx[tok]][l] + b2[l]
// One float4 (4 labels) per thread; 16 threads per token.
// ---------------------------------------------------------------------------
__global__ __launch_bounds__(256) void gather_out(
    const int* __restrict__ idx,
    const float* __restrict__ M,
    const float* __restrict__ b2,
    float* __restrict__ out,
    int ntok)
{
    int g   = blockIdx.x * 256 + threadIdx.x;
    int tok = g >> 4;
    int j   = g & 15;
    if (tok >= ntok) return;
    int v = idx[tok];
    float4 m = ((const float4*)M)[(size_t)v * 16 + j];
    float4 c = ((const float4*)b2)[j];
    ((float4*)out)[(size_t)tok * 16 + j] =
        make_float4(m.x + c.x, m.y + c.y, m.z + c.z, m.w + c.w);
}

// ---------------------------------------------------------------------------
// Fallback (only if ws too small for the table): direct per-token dot.
// ---------------------------------------------------------------------------
__global__ __launch_bounds__(256) void direct_kernel(
    const int* __restrict__ idx,
    const float* __restrict__ w1,
    const float* __restrict__ b1,
    const float* __restrict__ w2,
    const float* __restrict__ b2,
    float* __restrict__ out,
    int ntok)
{
    int g   = blockIdx.x * 256 + threadIdx.x;
    int tok = g >> 6;
    int l   = g & 63;
    if (tok >= ntok) return;
    int v = idx[tok];
    float acc = b2[l];
    for (int h = 0; h < HID; ++h)
        acc += (w1[(size_t)h * VOCAB + v] + b1[h]) * w2[l * HID + h];
    out[(size_t)tok * 64 + l] = acc;
}

extern "C" void kernel_launch(void* const* d_in, const int* in_sizes, int n_in,
                              void* d_out, int out_size, void* d_ws, size_t ws_size,
                              hipStream_t stream) {
    const int*   idx = (const int*)d_in[0];
    const float* w1  = (const float*)d_in[1];
    const float* b1  = (const float*)d_in[2];
    const float* w2  = (const float*)d_in[3];
    const float* b2  = (const float*)d_in[4];
    float* out = (float*)d_out;
    const int ntok = in_sizes[0];   // 8*4096 = 32768

    const size_t table_bytes = (size_t)VOCAB * LABELS * sizeof(float);  // ~12.9 MB

    if (ws_size >= table_bytes) {
        float* M = (float*)d_ws;
        int nblk1 = (VOCAB + 63) / 64;               // 786
        build_table<<<nblk1, 256, 0, stream>>>(w1, b1, w2, M);
        int nblk2 = (ntok * 16 + 255) / 256;         // 2048
        gather_out<<<nblk2, 256, 0, stream>>>(idx, M, b2, out, ntok);
    } else {
        int nblk = (ntok * 64 + 255) / 256;
        direct_kernel<<<nblk, 256, 0, stream>>>(idx, w1, b1, w2, b2, out, ntok);
    }
}

// Round 7
// 74.446 us; speedup vs baseline: 1.7350x; 1.7350x over previous
//
#include <hip/hip_runtime.h>
#include <hip/hip_bf16.h>

#define VOCAB 50257
#define HID 512
#define LABELS 64

// ---------------------------------------------------------------------------
// K1: partial tables P[s][v][l] = sum_{h in split s} (w1[h,v]+b1[h])*w2[l,h]
// Block: 64 vocab cols x 64 labels, K = klen (=512/ksplit), chunked by 32.
// 256 threads, 4x4 register tile each. Grid (786, ksplit) for occupancy.
// LDS stride 68: conflict-free staging writes and b128 compute reads.
// ---------------------------------------------------------------------------
__global__ __launch_bounds__(256) void build_partial(
    const float* __restrict__ w1,   // [HID][VOCAB]
    const float* __restrict__ b1,   // [HID]
    const float* __restrict__ w2,   // [LABELS][HID]
    float* __restrict__ P,          // [ksplit][VOCAB][LABELS]
    int klen)
{
    __shared__ float lds_a[32 * 68];  // [hh][col], b1 folded in
    __shared__ float lds_b[32 * 68];  // [hh][label]

    const int t     = threadIdx.x;
    const int v0    = blockIdx.x * 64;
    const int hbase = blockIdx.y * klen;
    float* Pout = P + (size_t)blockIdx.y * VOCAB * LABELS;
    const int tx = t & 15;   // cols tx*4 .. tx*4+3
    const int ty = t >> 4;   // labels ty*4 .. ty*4+3
    const bool full = (v0 + 64 <= VOCAB);

    float acc[4][4];
#pragma unroll
    for (int i = 0; i < 4; ++i)
#pragma unroll
        for (int j = 0; j < 4; ++j) acc[i][j] = 0.f;

    for (int h0 = hbase; h0 < hbase + klen; h0 += 32) {
        // ---- stage A (w1 chunk + b1): coalesced scalar loads, stride-1 LDS writes
#pragma unroll
        for (int i = 0; i < 8; ++i) {
            int e   = t + 256 * i;        // 0..2047
            int row = e >> 6;             // hh 0..31
            int col = e & 63;
            int v   = v0 + col;
            float a = (full || v < VOCAB) ? w1[(size_t)(h0 + row) * VOCAB + v] : 0.f;
            lds_a[row * 68 + col] = a + b1[h0 + row];
        }
        // ---- stage B (w2^T chunk): lane owns label l, float4 along h (16B aligned),
        //      4 scalar LDS writes at consecutive-l addresses -> conflict-free
#pragma unroll
        for (int i = 0; i < 2; ++i) {
            int e   = t + 256 * i;        // 0..511
            int hh4 = e >> 6;             // 0..7
            int l   = e & 63;
            float4 bv = *(const float4*)&w2[l * HID + h0 + hh4 * 4];
            lds_b[(hh4 * 4 + 0) * 68 + l] = bv.x;
            lds_b[(hh4 * 4 + 1) * 68 + l] = bv.y;
            lds_b[(hh4 * 4 + 2) * 68 + l] = bv.z;
            lds_b[(hh4 * 4 + 3) * 68 + l] = bv.w;
        }
        __syncthreads();

#pragma unroll
        for (int hh = 0; hh < 32; ++hh) {
            float4 a = *(const float4*)&lds_a[hh * 68 + tx * 4];
            float4 b = *(const float4*)&lds_b[hh * 68 + ty * 4];
            acc[0][0] += a.x * b.x; acc[0][1] += a.x * b.y; acc[0][2] += a.x * b.z; acc[0][3] += a.x * b.w;
            acc[1][0] += a.y * b.x; acc[1][1] += a.y * b.y; acc[1][2] += a.y * b.z; acc[1][3] += a.y * b.w;
            acc[2][0] += a.z * b.x; acc[2][1] += a.z * b.y; acc[2][2] += a.z * b.z; acc[2][3] += a.z * b.w;
            acc[3][0] += a.w * b.x; acc[3][1] += a.w * b.y; acc[3][2] += a.w * b.z; acc[3][3] += a.w * b.w;
        }
        __syncthreads();
    }

#pragma unroll
    for (int i = 0; i < 4; ++i) {
        int v = v0 + tx * 4 + i;
        if (v < VOCAB) {
            *(float4*)&Pout[(size_t)v * LABELS + ty * 4] =
                make_float4(acc[i][0], acc[i][1], acc[i][2], acc[i][3]);
        }
    }
}

// ---------------------------------------------------------------------------
// K2: out[tok][l] = sum_s P[s][idx[tok]][l] + b2[l]
// One float4 (4 labels) per thread; 16 threads per token. Partials L2/L3-hot.
// ---------------------------------------------------------------------------
__global__ __launch_bounds__(256) void gather_out(
    const int* __restrict__ idx,
    const float* __restrict__ P,
    const float* __restrict__ b2,
    float* __restrict__ out,
    int ntok, int ksplit)
{
    int g   = blockIdx.x * 256 + threadIdx.x;
    int tok = g >> 4;
    int j   = g & 15;
    if (tok >= ntok) return;
    int v = idx[tok];
    float4 s = ((const float4*)b2)[j];
    const float4* p = (const float4*)P + (size_t)v * 16 + j;
    for (int k = 0; k < ksplit; ++k) {
        float4 m = p[(size_t)k * VOCAB * 16];
        s.x += m.x; s.y += m.y; s.z += m.z; s.w += m.w;
    }
    ((float4*)out)[(size_t)tok * 16 + j] = s;
}

// ---------------------------------------------------------------------------
// Fallback (ws too small for even one table): direct per-token dot.
// ---------------------------------------------------------------------------
__global__ __launch_bounds__(256) void direct_kernel(
    const int* __restrict__ idx,
    const float* __restrict__ w1,
    const float* __restrict__ b1,
    const float* __restrict__ w2,
    const float* __restrict__ b2,
    float* __restrict__ out,
    int ntok)
{
    int g   = blockIdx.x * 256 + threadIdx.x;
    int tok = g >> 6;
    int l   = g & 63;
    if (tok >= ntok) return;
    int v = idx[tok];
    float acc = b2[l];
    for (int h = 0; h < HID; ++h)
        acc += (w1[(size_t)h * VOCAB + v] + b1[h]) * w2[l * HID + h];
    out[(size_t)tok * 64 + l] = acc;
}

extern "C" void kernel_launch(void* const* d_in, const int* in_sizes, int n_in,
                              void* d_out, int out_size, void* d_ws, size_t ws_size,
                              hipStream_t stream) {
    const int*   idx = (const int*)d_in[0];
    const float* w1  = (const float*)d_in[1];
    const float* b1  = (const float*)d_in[2];
    const float* w2  = (const float*)d_in[3];
    const float* b2  = (const float*)d_in[4];
    float* out = (float*)d_out;
    const int ntok = in_sizes[0];   // 8*4096 = 32768

    const size_t table_bytes = (size_t)VOCAB * LABELS * sizeof(float);  // ~12.9 MB

    int ksplit = 0;
    if      (ws_size >= 4 * table_bytes) ksplit = 4;
    else if (ws_size >= 2 * table_bytes) ksplit = 2;
    else if (ws_size >= 1 * table_bytes) ksplit = 1;

    if (ksplit > 0) {
        float* P = (float*)d_ws;
        int klen  = HID / ksplit;
        dim3 grid1((VOCAB + 63) / 64, ksplit);   // 786 x ksplit
        build_partial<<<grid1, 256, 0, stream>>>(w1, b1, w2, P, klen);
        int nblk2 = (ntok * 16 + 255) / 256;     // 2048
        gather_out<<<nblk2, 256, 0, stream>>>(idx, P, b2, out, ntok, ksplit);
    } else {
        int nblk = (ntok * 64 + 255) / 256;
        direct_kernel<<<nblk, 256, 0, stream>>>(idx, w1, b1, w2, b2, out, ntok);
    }
}